// Round 12
// baseline (373.207 us; speedup 1.0000x reference)
//
#include <hip/hip_runtime.h>
#include <hip/hip_bf16.h>
#include <math.h>

#define SCALE 0.08838834764831845f  // 1/sqrt(128)

using short8  = __attribute__((ext_vector_type(8))) short;
using short4v = __attribute__((ext_vector_type(4))) short;
using us4     = __attribute__((ext_vector_type(4))) unsigned short;
using f32x4   = __attribute__((ext_vector_type(4))) float;
typedef unsigned long long u64;
typedef unsigned short ushort_t;

static __device__ __forceinline__ ushort_t bf16_of(float f) {
    __hip_bfloat16 h = __float2bfloat16(f);
    return *reinterpret_cast<ushort_t*>(&h);
}
static __device__ __forceinline__ float f_of_bf16(unsigned int u) {
    union { unsigned int i; float f; } v; v.i = u << 16; return v.f;
}

// ---------------- fused prep kernel ----------------
// grid 3120 x 256:
//   [0,1024)    : x -> bf16, plus column partial-sums into xsum[b][e]
//   [1024,1072) : W -> bf16 transposed [3072][128]
//   [1072,3120) : mask bit-pack (8192 rows x 16 u64)
__global__ __launch_bounds__(256)
void prep_all(const float* __restrict__ x, ushort_t* __restrict__ xb,
              const float* __restrict__ wq, const float* __restrict__ wk,
              const float* __restrict__ wv, ushort_t* __restrict__ Wt,
              const int* __restrict__ mask, u64* __restrict__ mp,
              float* __restrict__ xsum) {
    __shared__ float tile[64][129];
    __shared__ float csum[128];
    const int bx = blockIdx.x;
    const int tid = threadIdx.x;
    if (bx < 1024) {
        const int i = bx * 256 + tid;
        float4 v = reinterpret_cast<const float4*>(x)[i];
        short4v o;
        o.x = (short)bf16_of(v.x); o.y = (short)bf16_of(v.y);
        o.z = (short)bf16_of(v.z); o.w = (short)bf16_of(v.w);
        reinterpret_cast<short4v*>(xb)[i] = o;
        // column partials: block covers 8 rows of one batch; e0 = (tid&31)*4
        if (tid < 128) csum[tid] = 0.f;
        __syncthreads();
        const int e0 = (tid & 31) * 4;
        atomicAdd(&csum[e0 + 0], v.x);
        atomicAdd(&csum[e0 + 1], v.y);
        atomicAdd(&csum[e0 + 2], v.z);
        atomicAdd(&csum[e0 + 3], v.w);
        __syncthreads();
        if (tid < 128) atomicAdd(&xsum[(bx >> 7) * 128 + tid], csum[tid]);
    } else if (bx < 1072) {
        const int wb = bx - 1024;
        const int mat = wb >> 4;
        const int n0 = (wb & 15) * 64;
        const float* W = (mat == 0) ? wq : (mat == 1) ? wk : wv;
        for (int idx = tid; idx < 8192; idx += 256) {
            const int k = idx >> 6, c = idx & 63;
            tile[c][k] = W[(size_t)k * 1024 + n0 + c];
        }
        __syncthreads();
        for (int idx = tid; idx < 8192; idx += 256) {
            const int c = idx >> 7, k = idx & 127;
            Wt[(size_t)(mat * 1024 + n0 + c) * 128 + k] = bf16_of(tile[c][k]);
        }
    } else {
        const int mb = bx - 1072;
        const int row = mb * 4 + (tid >> 6);
        const int l = tid & 63;
        const int* m = mask + (size_t)row * 1024;
        #pragma unroll
        for (int c = 0; c < 16; ++c) {
            u64 bm = __ballot(m[c * 64 + l] != 0);
            if (l == 0) mp[(size_t)row * 16 + c] = bm;
        }
    }
}

// ---------------- MFMA projection GEMM ----------------
// grid (128, 48), block 256 (4 waves). mat = blockIdx.y>>4 (0 Q,1 K,2 V).
// All outputs row-major bf16 [hb][t][128]; Q pre-scaled.
__global__ __launch_bounds__(256)
void proj_gemm(const ushort_t* __restrict__ xb, const ushort_t* __restrict__ Wt,
               ushort_t* __restrict__ Q, ushort_t* __restrict__ K,
               ushort_t* __restrict__ V) {
    const int tid = threadIdx.x;
    const int w = tid >> 6, l = tid & 63;
    const int l15 = l & 15, lq = l >> 4;
    const int m0 = blockIdx.x * 64;
    const int nb = blockIdx.y;
    const int mat = nb >> 4;
    const int n0 = (nb & 15) * 64;
    const int b = m0 >> 10;

    short8 af[4][4];
    #pragma unroll
    for (int at = 0; at < 4; ++at) {
        const ushort_t* ar = xb + (size_t)(m0 + at * 16 + l15) * 128 + lq * 8;
        #pragma unroll
        for (int f = 0; f < 4; ++f)
            af[at][f] = *reinterpret_cast<const short8*>(ar + f * 32);
    }
    const int ng = n0 + w * 16 + l15;
    const ushort_t* br = Wt + (size_t)(mat * 1024 + ng) * 128 + lq * 8;
    short8 bf[4];
    #pragma unroll
    for (int f = 0; f < 4; ++f)
        bf[f] = *reinterpret_cast<const short8*>(br + f * 32);
    f32x4 acc[4];
    #pragma unroll
    for (int at = 0; at < 4; ++at) acc[at] = (f32x4){0.f, 0.f, 0.f, 0.f};
    #pragma unroll
    for (int at = 0; at < 4; ++at)
        #pragma unroll
        for (int f = 0; f < 4; ++f)
            acc[at] = __builtin_amdgcn_mfma_f32_16x16x32_bf16(af[at][f], bf[f], acc[at], 0, 0, 0);

    const int h = ng >> 7, e = ng & 127;
    ushort_t* O = (mat == 0) ? Q : (mat == 1) ? K : V;
    const float scl = (mat == 0) ? SCALE : 1.0f;
    const size_t obase = (size_t)(h * 8 + b) * 131072 + e;
    #pragma unroll
    for (int at = 0; at < 4; ++at)
        #pragma unroll
        for (int r = 0; r < 4; ++r) {
            const int t = (m0 & 1023) + at * 16 + lq * 4 + r;
            O[obase + (size_t)t * 128] = bf16_of(acc[at][r] * scl);
        }
}

// ---------------- sel finalize (tiny) ----------------
__global__ __launch_bounds__(128)
void sel_final(const float* __restrict__ xsum, const float* __restrict__ wsl,
               const float* __restrict__ bsl, float* __restrict__ sel) {
    __shared__ float xm[128];
    __shared__ float lg[8];
    const int b = blockIdx.x;
    const int tid = threadIdx.x;
    xm[tid] = xsum[b * 128 + tid] * (1.0f / 1024.0f);
    __syncthreads();
    if (tid < 8) {
        float d = 0.f;
        for (int e = 0; e < 128; ++e) d += xm[e] * wsl[tid * 128 + e];
        lg[tid] = d + bsl[tid];
    }
    __syncthreads();
    if (tid == 0) {
        float mx = lg[0];
        for (int hh = 1; hh < 8; ++hh) mx = fmaxf(mx, lg[hh]);
        float se = 0.f; float ex[8];
        for (int hh = 0; hh < 8; ++hh) { ex[hh] = expf(lg[hh] - mx); se += ex[hh]; }
        for (int hh = 0; hh < 8; ++hh) sel[b * 8 + hh] = ex[hh] / se;
    }
}

// ---------------- MFMA attention: round-8 structure + next-head pipeline ----------
// grid 512 = 8 batches * 64 q-tiles; block 512 (8 waves); head loop inside.
// XCD x owns batch b=x (L2-resident per-head K/Q/V, ~2 heads in flight).
__global__ __launch_bounds__(512, 4)
void attn_kernel(const ushort_t* __restrict__ Qb, const ushort_t* __restrict__ Kb,
                 const ushort_t* __restrict__ Vb, const u64* __restrict__ mp,
                 const float* __restrict__ sel, float* __restrict__ out) {
    __shared__ float S[16 * 1024];   // 64 KB; support list aliases it
    __shared__ int cnt[16];
    unsigned int* list = reinterpret_cast<unsigned int*>(S);

    const int tid = threadIdx.x;
    const int w = tid >> 6, l = tid & 63;
    const int l15 = l & 15, lq = l >> 4;
    const int orig = (int)blockIdx.x;
    const int swz = (orig & 7) * 64 + (orig >> 3);   // XCD-chunked remap (512 % 8 == 0)
    const int b = swz >> 6;                          // batch locked to XCD
    const int qt = swz & 63;
    const int t0 = qt * 16;
    const int rowbase = b * 1024 + t0;

    const int qrow = 2 * w + (l & 1);   // row for transpose/solve/compact (parity)
    const int lh = l >> 1;
    const int prow = tid >> 5;          // row for PV (same wave's rows)
    const int eq = tid & 31;

    if (tid < 16) cnt[tid] = 0;

    // ---- hoist head-invariant mask words: rows q=lq*4+r, words w*2, w*2+1 ----
    u64 mw0[4], mw1[4];
    #pragma unroll
    for (int r = 0; r < 4; ++r) {
        const u64* mrow = mp + (size_t)(rowbase + lq * 4 + r) * 16 + w * 2;
        mw0[r] = mrow[0];
        mw1[r] = mrow[1];
    }

    // ---- prologue: QK^T for head 0 ----
    f32x4 sc[8];
    {
        const size_t base0 = (size_t)b * 131072;     // h=0
        short8 qa[4];
        const ushort_t* qrp = Qb + base0 + (size_t)(t0 + l15) * 128 + lq * 8;
        #pragma unroll
        for (int f = 0; f < 4; ++f)
            qa[f] = *reinterpret_cast<const short8*>(qrp + f * 32);
        #pragma unroll
        for (int i = 0; i < 8; ++i) {
            const int kt = w * 8 + i;
            const ushort_t* krow = Kb + base0 + (size_t)(kt * 16 + l15) * 128 + lq * 8;
            f32x4 acc = {0.f, 0.f, 0.f, 0.f};
            #pragma unroll
            for (int f = 0; f < 4; ++f) {
                short8 kb = *reinterpret_cast<const short8*>(krow + f * 32);
                acc = __builtin_amdgcn_mfma_f32_16x16x32_bf16(qa[f], kb, acc, 0, 0, 0);
            }
            sc[i] = acc;
        }
    }

    f32x4 oac = {0.f, 0.f, 0.f, 0.f};   // gated head-sum accumulator (prow, eq*4..+3)

    #pragma unroll
    for (int h = 0; h < 8; ++h) {
        const size_t base = (size_t)(h * 8 + b) * 131072;

        // ---- mask (hoisted words; bit=1 -> -1e30) ----
        #pragma unroll
        for (int r = 0; r < 4; ++r) {
            #pragma unroll
            for (int i = 0; i < 8; ++i) {
                const u64 mword = (i < 4) ? mw0[r] : mw1[r];
                const int bit = (i & 3) * 16 + l15;
                if ((mword >> bit) & 1ULL) sc[i][r] = -1e30f;
            }
        }

        __syncthreads();   // prev head's list reads done before S overwrite

        // ---- S store (f32, chunk-swizzled) ----
        #pragma unroll
        for (int r = 0; r < 4; ++r) {
            const int q = lq * 4 + r;
            #pragma unroll
            for (int i = 0; i < 8; ++i) {
                const int c = (w * 8 + i) * 4 + (l15 >> 2);
                const int cp = c ^ ((c >> 3) & 7) ^ (q & 7);
                S[q * 1024 + cp * 4 + (l15 & 3)] = sc[i][r];
            }
        }
        __syncthreads();

        // ---- transpose read: lane owns 32 vals of row qrow; z[4j+m] = col 4*lh+128*j+m ----
        float z[32];
        #pragma unroll
        for (int j = 0; j < 8; ++j) {
            const int c = lh + 32 * j;
            const int cp = c ^ ((c >> 3) & 7) ^ (qrow & 7);
            float4 v = *reinterpret_cast<const float4*>(&S[qrow * 1024 + cp * 4]);
            z[4 * j + 0] = v.x; z[4 * j + 1] = v.y;
            z[4 * j + 2] = v.z; z[4 * j + 3] = v.w;
        }
        // rows are wave-private from here (solve/compact/PV touch only rows 2w,2w+1)

        // ---- PIPELINE: issue next head's QK^T now (global+MFMA only, no LDS) ----
        f32x4 scn[8];
        if (h < 7) {
            const size_t nbase = (size_t)((h + 1) * 8 + b) * 131072;
            short8 qn[4];
            const ushort_t* qrp = Qb + nbase + (size_t)(t0 + l15) * 128 + lq * 8;
            #pragma unroll
            for (int f = 0; f < 4; ++f)
                qn[f] = *reinterpret_cast<const short8*>(qrp + f * 32);
            #pragma unroll
            for (int i = 0; i < 8; ++i) {
                const int kt = w * 8 + i;
                const ushort_t* krow = Kb + nbase + (size_t)(kt * 16 + l15) * 128 + lq * 8;
                f32x4 acc = {0.f, 0.f, 0.f, 0.f};
                #pragma unroll
                for (int f = 0; f < 4; ++f) {
                    short8 kb = *reinterpret_cast<const short8*>(krow + f * 32);
                    acc = __builtin_amdgcn_mfma_f32_16x16x32_bf16(qn[f], kb, acc, 0, 0, 0);
                }
                scn[i] = acc;
            }
        }

        // ---- row max (tree + 5 same-parity shfl) ----
        float m16[16];
        #pragma unroll
        for (int j = 0; j < 16; ++j) m16[j] = fmaxf(z[j], z[j + 16]);
        #pragma unroll
        for (int j = 0; j < 8; ++j) m16[j] = fmaxf(m16[j], m16[j + 8]);
        #pragma unroll
        for (int j = 0; j < 4; ++j) m16[j] = fmaxf(m16[j], m16[j + 4]);
        float mx = fmaxf(fmaxf(m16[0], m16[1]), fmaxf(m16[2], m16[3]));
        #pragma unroll
        for (int mm = 2; mm < 64; mm <<= 1) mx = fmaxf(mx, __shfl_xor(mx, mm));

        // ---- Michelot sparsemax, warm start from {z > mx-1} (superset of support) ----
        float tau;
        if (mx < -1e29f) {
            tau = 3e38f;               // fully-masked row -> zero output
        } else {
            tau = mx - 1.0f;
            unsigned prev = 0xFFFFFFFFu;
            for (int it = 0; it < 64; ++it) {
                float s2 = 0.f; unsigned c2 = 0u;
                #pragma unroll
                for (int k = 0; k < 32; ++k) {
                    const float zz = z[k];
                    s2 += (zz > tau) ? zz : 0.f;
                    c2 += (zz > tau) ? 1u : 0u;
                }
                #pragma unroll
                for (int mm = 2; mm < 64; mm <<= 1) {
                    s2 += __shfl_xor(s2, mm);
                    c2 += __shfl_xor(c2, mm);
                }
                if (c2 == prev) break;
                tau = (s2 - 1.f) / (float)c2;
                prev = c2;
            }
        }

        // ---- compact support (k, p-bf16) into list rows 2w,2w+1 (wave-private) ----
        #pragma unroll
        for (int jj = 0; jj < 32; ++jj) {
            const float p = z[jj] - tau;
            if (p > 0.f) {
                const int k = 4 * lh + 128 * (jj >> 2) + (jj & 3);
                const int pos = atomicAdd(&cnt[qrow], 1);
                list[qrow * 1024 + pos] = (unsigned int)k | ((unsigned int)bf16_of(p) << 16);
            }
        }
        // same-wave RAW on cnt/list -> no barrier

        // ---- sparse PV (unroll x2): half-wave = row, lane = e-quad ----
        const float gsel = sel[b * 8 + h];
        const int n = cnt[prow];
        const ushort_t* Vrow = Vb + base;
        const unsigned int* lrow = list + prow * 1024;
        float a0 = 0.f, a1 = 0.f, a2 = 0.f, a3 = 0.f;
        float b0 = 0.f, b1 = 0.f, b2 = 0.f, b3 = 0.f;
        int j = 0;
        for (; j + 2 <= n; j += 2) {
            const unsigned int e0 = lrow[j];
            const unsigned int e1 = lrow[j + 1];
            const int k0 = (int)(e0 & 0xFFFFu);
            const int k1 = (int)(e1 & 0xFFFFu);
            const float g0 = gsel * f_of_bf16(e0 >> 16);
            const float g1 = gsel * f_of_bf16(e1 >> 16);
            us4 v0 = *reinterpret_cast<const us4*>(Vrow + (size_t)k0 * 128 + eq * 4);
            us4 v1 = *reinterpret_cast<const us4*>(Vrow + (size_t)k1 * 128 + eq * 4);
            a0 += g0 * f_of_bf16(v0.x); a1 += g0 * f_of_bf16(v0.y);
            a2 += g0 * f_of_bf16(v0.z); a3 += g0 * f_of_bf16(v0.w);
            b0 += g1 * f_of_bf16(v1.x); b1 += g1 * f_of_bf16(v1.y);
            b2 += g1 * f_of_bf16(v1.z); b3 += g1 * f_of_bf16(v1.w);
        }
        if (j < n) {
            const unsigned int e0 = lrow[j];
            const int k0 = (int)(e0 & 0xFFFFu);
            const float g0 = gsel * f_of_bf16(e0 >> 16);
            us4 v0 = *reinterpret_cast<const us4*>(Vrow + (size_t)k0 * 128 + eq * 4);
            a0 += g0 * f_of_bf16(v0.x); a1 += g0 * f_of_bf16(v0.y);
            a2 += g0 * f_of_bf16(v0.z); a3 += g0 * f_of_bf16(v0.w);
        }
        oac[0] += a0 + b0; oac[1] += a1 + b1;
        oac[2] += a2 + b2; oac[3] += a3 + b3;

        if (eq == 0) cnt[prow] = 0;   // reset by owning half-wave (in-order after reads)

        // ---- rotate pipeline ----
        if (h < 7) {
            #pragma unroll
            for (int i = 0; i < 8; ++i) sc[i] = scn[i];
        }
    }

    // ---- single plain store (no atomics, every element covered exactly once) ----
    float* orow = out + ((size_t)(b * 1024 + t0 + prow)) * 128 + eq * 4;
    *reinterpret_cast<float4*>(orow) = (float4){oac[0], oac[1], oac[2], oac[3]};
}

extern "C" void kernel_launch(void* const* d_in, const int* in_sizes, int n_in,
                              void* d_out, int out_size, void* d_ws, size_t ws_size,
                              hipStream_t stream) {
    (void)in_sizes; (void)n_in; (void)ws_size; (void)out_size;
    const float* x   = (const float*)d_in[0];
    const int* mask  = (const int*)d_in[1];
    const float* wq  = (const float*)d_in[2];
    const float* wk  = (const float*)d_in[3];
    const float* wv  = (const float*)d_in[4];
    const float* wsl = (const float*)d_in[5];
    const float* bsl = (const float*)d_in[6];
    float* out = (float*)d_out;

    // ws layout (fixed): sel 1KB @0 | xsum 4KB @1024 | pad | mp 1MB @8192
    //                    | xb 2MB | Wt 768KB | Q 16MB | K 16MB | V 16MB
    char* wsc = (char*)d_ws;
    float*    sel  = (float*)wsc;
    float*    xsum = (float*)(wsc + 1024);
    u64*      mp   = (u64*)(wsc + 8192);
    ushort_t* xb   = (ushort_t*)(wsc + 8192 + 1048576);
    ushort_t* Wt   = (ushort_t*)(wsc + 8192 + 1048576 + 2097152);
    ushort_t* Qb   = (ushort_t*)(wsc + 8192 + 1048576 + 2097152 + 786432);
    ushort_t* Kb   = Qb + (size_t)8388608;
    ushort_t* Vb   = Kb + (size_t)8388608;

    hipMemsetAsync(xsum, 0, 4096, stream);
    prep_all<<<3120, 256, 0, stream>>>(x, xb, wq, wk, wv, Wt, mask, mp, xsum);
    proj_gemm<<<dim3(128, 48), 256, 0, stream>>>(xb, Wt, Qb, Kb, Vb);
    sel_final<<<8, 128, 0, stream>>>(xsum, wsl, bsl, sel);
    attn_kernel<<<512, 512, 0, stream>>>(Qb, Kb, Vb, mp, sel, out);
}

// Round 13
// 291.252 us; speedup vs baseline: 1.2814x; 1.2814x over previous
//
#include <hip/hip_runtime.h>
#include <hip/hip_bf16.h>
#include <math.h>

#define SCALE 0.08838834764831845f  // 1/sqrt(128)

using short8  = __attribute__((ext_vector_type(8))) short;
using short4v = __attribute__((ext_vector_type(4))) short;
using us4     = __attribute__((ext_vector_type(4))) unsigned short;
using f32x4   = __attribute__((ext_vector_type(4))) float;
typedef unsigned long long u64;
typedef unsigned short ushort_t;

static __device__ __forceinline__ ushort_t bf16_of(float f) {
    __hip_bfloat16 h = __float2bfloat16(f);
    return *reinterpret_cast<ushort_t*>(&h);
}
static __device__ __forceinline__ float f_of_bf16(unsigned int u) {
    union { unsigned int i; float f; } v; v.i = u << 16; return v.f;
}

// ---------------- fused prep kernel ----------------
// grid 3120 x 256:
//   [0,1024)    : x -> bf16, plus column partial-sums into xsum[b][e]
//   [1024,1072) : W -> bf16 transposed [3072][128]
//   [1072,3120) : mask bit-pack (8192 rows x 16 u64)
__global__ __launch_bounds__(256)
void prep_all(const float* __restrict__ x, ushort_t* __restrict__ xb,
              const float* __restrict__ wq, const float* __restrict__ wk,
              const float* __restrict__ wv, ushort_t* __restrict__ Wt,
              const int* __restrict__ mask, u64* __restrict__ mp,
              float* __restrict__ xsum) {
    __shared__ float tile[64][129];
    __shared__ float csum[128];
    const int bx = blockIdx.x;
    const int tid = threadIdx.x;
    if (bx < 1024) {
        const int i = bx * 256 + tid;
        float4 v = reinterpret_cast<const float4*>(x)[i];
        short4v o;
        o.x = (short)bf16_of(v.x); o.y = (short)bf16_of(v.y);
        o.z = (short)bf16_of(v.z); o.w = (short)bf16_of(v.w);
        reinterpret_cast<short4v*>(xb)[i] = o;
        // column partials: block covers 8 rows of one batch; e0 = (tid&31)*4
        if (tid < 128) csum[tid] = 0.f;
        __syncthreads();
        const int e0 = (tid & 31) * 4;
        atomicAdd(&csum[e0 + 0], v.x);
        atomicAdd(&csum[e0 + 1], v.y);
        atomicAdd(&csum[e0 + 2], v.z);
        atomicAdd(&csum[e0 + 3], v.w);
        __syncthreads();
        if (tid < 128) atomicAdd(&xsum[(bx >> 7) * 128 + tid], csum[tid]);
    } else if (bx < 1072) {
        const int wb = bx - 1024;
        const int mat = wb >> 4;
        const int n0 = (wb & 15) * 64;
        const float* W = (mat == 0) ? wq : (mat == 1) ? wk : wv;
        for (int idx = tid; idx < 8192; idx += 256) {
            const int k = idx >> 6, c = idx & 63;
            tile[c][k] = W[(size_t)k * 1024 + n0 + c];
        }
        __syncthreads();
        for (int idx = tid; idx < 8192; idx += 256) {
            const int c = idx >> 7, k = idx & 127;
            Wt[(size_t)(mat * 1024 + n0 + c) * 128 + k] = bf16_of(tile[c][k]);
        }
    } else {
        const int mb = bx - 1072;
        const int row = mb * 4 + (tid >> 6);
        const int l = tid & 63;
        const int* m = mask + (size_t)row * 1024;
        #pragma unroll
        for (int c = 0; c < 16; ++c) {
            u64 bm = __ballot(m[c * 64 + l] != 0);
            if (l == 0) mp[(size_t)row * 16 + c] = bm;
        }
    }
}

// ---------------- MFMA projection GEMM ----------------
// grid (128, 48), block 256 (4 waves). mat = blockIdx.y>>4 (0 Q,1 K,2 V).
// All outputs row-major bf16 [hb][t][128]; Q pre-scaled.
__global__ __launch_bounds__(256)
void proj_gemm(const ushort_t* __restrict__ xb, const ushort_t* __restrict__ Wt,
               ushort_t* __restrict__ Q, ushort_t* __restrict__ K,
               ushort_t* __restrict__ V) {
    const int tid = threadIdx.x;
    const int w = tid >> 6, l = tid & 63;
    const int l15 = l & 15, lq = l >> 4;
    const int m0 = blockIdx.x * 64;
    const int nb = blockIdx.y;
    const int mat = nb >> 4;
    const int n0 = (nb & 15) * 64;
    const int b = m0 >> 10;

    short8 af[4][4];
    #pragma unroll
    for (int at = 0; at < 4; ++at) {
        const ushort_t* ar = xb + (size_t)(m0 + at * 16 + l15) * 128 + lq * 8;
        #pragma unroll
        for (int f = 0; f < 4; ++f)
            af[at][f] = *reinterpret_cast<const short8*>(ar + f * 32);
    }
    const int ng = n0 + w * 16 + l15;
    const ushort_t* br = Wt + (size_t)(mat * 1024 + ng) * 128 + lq * 8;
    short8 bf[4];
    #pragma unroll
    for (int f = 0; f < 4; ++f)
        bf[f] = *reinterpret_cast<const short8*>(br + f * 32);
    f32x4 acc[4];
    #pragma unroll
    for (int at = 0; at < 4; ++at) acc[at] = (f32x4){0.f, 0.f, 0.f, 0.f};
    #pragma unroll
    for (int at = 0; at < 4; ++at)
        #pragma unroll
        for (int f = 0; f < 4; ++f)
            acc[at] = __builtin_amdgcn_mfma_f32_16x16x32_bf16(af[at][f], bf[f], acc[at], 0, 0, 0);

    const int h = ng >> 7, e = ng & 127;
    ushort_t* O = (mat == 0) ? Q : (mat == 1) ? K : V;
    const float scl = (mat == 0) ? SCALE : 1.0f;
    const size_t obase = (size_t)(h * 8 + b) * 131072 + e;
    #pragma unroll
    for (int at = 0; at < 4; ++at)
        #pragma unroll
        for (int r = 0; r < 4; ++r) {
            const int t = (m0 & 1023) + at * 16 + lq * 4 + r;
            O[obase + (size_t)t * 128] = bf16_of(acc[at][r] * scl);
        }
}

// ---------------- sel finalize (tiny) ----------------
__global__ __launch_bounds__(128)
void sel_final(const float* __restrict__ xsum, const float* __restrict__ wsl,
               const float* __restrict__ bsl, float* __restrict__ sel) {
    __shared__ float xm[128];
    __shared__ float lg[8];
    const int b = blockIdx.x;
    const int tid = threadIdx.x;
    xm[tid] = xsum[b * 128 + tid] * (1.0f / 1024.0f);
    __syncthreads();
    if (tid < 8) {
        float d = 0.f;
        for (int e = 0; e < 128; ++e) d += xm[e] * wsl[tid * 128 + e];
        lg[tid] = d + bsl[tid];
    }
    __syncthreads();
    if (tid == 0) {
        float mx = lg[0];
        for (int hh = 1; hh < 8; ++hh) mx = fmaxf(mx, lg[hh]);
        float se = 0.f; float ex[8];
        for (int hh = 0; hh < 8; ++hh) { ex[hh] = expf(lg[hh] - mx); se += ex[hh]; }
        for (int hh = 0; hh < 8; ++hh) sel[b * 8 + hh] = ex[hh] / se;
    }
}

// ---------------- MFMA attention: round-8 structure + candidate-register solve ------
// grid 512 = 8 batches * 64 q-tiles; block 512 (8 waves); head loop inside (no unroll).
// XCD x owns batch b=x (L2-resident per-head K/Q/V, ~2 heads in flight).
__global__ __launch_bounds__(512, 4)
void attn_kernel(const ushort_t* __restrict__ Qb, const ushort_t* __restrict__ Kb,
                 const ushort_t* __restrict__ Vb, const u64* __restrict__ mp,
                 const float* __restrict__ sel, float* __restrict__ out) {
    __shared__ float S[16 * 1024];   // 64 KB; support list aliases it
    __shared__ int cnt[16];
    unsigned int* list = reinterpret_cast<unsigned int*>(S);

    const int tid = threadIdx.x;
    const int w = tid >> 6, l = tid & 63;
    const int l15 = l & 15, lq = l >> 4;
    const int orig = (int)blockIdx.x;
    const int swz = (orig & 7) * 64 + (orig >> 3);   // XCD-chunked remap (512 % 8 == 0)
    const int b = swz >> 6;                          // batch locked to XCD
    const int qt = swz & 63;
    const int t0 = qt * 16;
    const int rowbase = b * 1024 + t0;

    const int qrow = 2 * w + (l & 1);   // row for transpose/solve/compact (parity)
    const int lh = l >> 1;
    const int prow = tid >> 5;          // row for PV (same wave's rows)
    const int eq = tid & 31;

    if (tid < 16) cnt[tid] = 0;

    // ---- hoist head-invariant mask words: rows q=lq*4+r, words w*2, w*2+1 ----
    u64 mw0[4], mw1[4];
    #pragma unroll
    for (int r = 0; r < 4; ++r) {
        const u64* mrow = mp + (size_t)(rowbase + lq * 4 + r) * 16 + w * 2;
        mw0[r] = mrow[0];
        mw1[r] = mrow[1];
    }

    f32x4 oac = {0.f, 0.f, 0.f, 0.f};   // gated head-sum accumulator (prow, eq*4..+3)

    for (int h = 0; h < 8; ++h) {
        const size_t base = (size_t)(h * 8 + b) * 131072;
        __syncthreads();   // prev head's list reads done before S overwrite

        // ---- Q A-frags ----
        short8 qa[4];
        {
            const ushort_t* qrp = Qb + base + (size_t)(t0 + l15) * 128 + lq * 8;
            #pragma unroll
            for (int f = 0; f < 4; ++f)
                qa[f] = *reinterpret_cast<const short8*>(qrp + f * 32);
        }

        // ---- QK^T: sc[i][r] = S[q=lq*4+r][k=(w*8+i)*16+l15] ----
        f32x4 sc[8];
        #pragma unroll
        for (int i = 0; i < 8; ++i) {
            const int kt = w * 8 + i;
            const ushort_t* krow = Kb + base + (size_t)(kt * 16 + l15) * 128 + lq * 8;
            f32x4 acc = {0.f, 0.f, 0.f, 0.f};
            #pragma unroll
            for (int f = 0; f < 4; ++f) {
                short8 kb = *reinterpret_cast<const short8*>(krow + f * 32);
                acc = __builtin_amdgcn_mfma_f32_16x16x32_bf16(qa[f], kb, acc, 0, 0, 0);
            }
            sc[i] = acc;
        }

        // ---- mask (hoisted words; bit=1 -> -1e30) ----
        #pragma unroll
        for (int r = 0; r < 4; ++r) {
            #pragma unroll
            for (int i = 0; i < 8; ++i) {
                const u64 mword = (i < 4) ? mw0[r] : mw1[r];
                const int bit = (i & 3) * 16 + l15;
                if ((mword >> bit) & 1ULL) sc[i][r] = -1e30f;
            }
        }

        // ---- S store (f32, chunk-swizzled) ----
        #pragma unroll
        for (int r = 0; r < 4; ++r) {
            const int q = lq * 4 + r;
            #pragma unroll
            for (int i = 0; i < 8; ++i) {
                const int c = (w * 8 + i) * 4 + (l15 >> 2);
                const int cp = c ^ ((c >> 3) & 7) ^ (q & 7);
                S[q * 1024 + cp * 4 + (l15 & 3)] = sc[i][r];
            }
        }
        __syncthreads();

        // ---- transpose read: lane owns 32 vals of row qrow; z[4j+m] = col 4*lh+128*j+m ----
        float z[32];
        #pragma unroll
        for (int j = 0; j < 8; ++j) {
            const int c = lh + 32 * j;
            const int cp = c ^ ((c >> 3) & 7) ^ (qrow & 7);
            float4 v = *reinterpret_cast<const float4*>(&S[qrow * 1024 + cp * 4]);
            z[4 * j + 0] = v.x; z[4 * j + 1] = v.y;
            z[4 * j + 2] = v.z; z[4 * j + 3] = v.w;
        }
        // rows are wave-private from here (solve/compact/PV touch only rows 2w,2w+1)

        // ---- row max (tree + 5 same-parity shfl) ----
        float m16[16];
        #pragma unroll
        for (int j = 0; j < 16; ++j) m16[j] = fmaxf(z[j], z[j + 16]);
        #pragma unroll
        for (int j = 0; j < 8; ++j) m16[j] = fmaxf(m16[j], m16[j + 8]);
        #pragma unroll
        for (int j = 0; j < 4; ++j) m16[j] = fmaxf(m16[j], m16[j + 4]);
        float mx = fmaxf(fmaxf(m16[0], m16[1]), fmaxf(m16[2], m16[3]));
        #pragma unroll
        for (int mm = 2; mm < 64; mm <<= 1) mx = fmaxf(mx, __shfl_xor(mx, mm));

        // ---- candidate collection: support subset {z > mx-1} (tau* >= mx-1) ----
        const float thr = mx - 1.0f;
        float cv0 = -1e30f, cv1 = -1e30f, cv2 = -1e30f, cv3 = -1e30f;
        int   ck0 = 0, ck1 = 0, ck2 = 0, ck3 = 0;
        int   nc = 0;
        #pragma unroll
        for (int jj = 0; jj < 32; ++jj) {
            const float zz = z[jj];
            if (zz > thr) {
                const int kk = 4 * lh + 128 * (jj >> 2) + (jj & 3);
                if (nc == 0)      { cv0 = zz; ck0 = kk; }
                else if (nc == 1) { cv1 = zz; ck1 = kk; }
                else if (nc == 2) { cv2 = zz; ck2 = kk; }
                else if (nc == 3) { cv3 = zz; ck3 = kk; }
                ++nc;
            }
        }

        float tau;
        const bool fullrow_masked = (mx < -1e29f);
        if (__any(nc > 4)) {
            // ---- fallback: exact full-scan Michelot (rare: >4 candidates in a lane) ----
            if (fullrow_masked) {
                tau = 3e38f;
            } else {
                tau = thr;
                unsigned prev = 0xFFFFFFFFu;
                for (int it = 0; it < 64; ++it) {
                    float s2 = 0.f; unsigned c2 = 0u;
                    #pragma unroll
                    for (int k = 0; k < 32; ++k) {
                        const float zz = z[k];
                        s2 += (zz > tau) ? zz : 0.f;
                        c2 += (zz > tau) ? 1u : 0u;
                    }
                    #pragma unroll
                    for (int mm = 2; mm < 64; mm <<= 1) {
                        s2 += __shfl_xor(s2, mm);
                        c2 += __shfl_xor(c2, mm);
                    }
                    if (c2 == prev) break;
                    tau = (s2 - 1.f) / (float)c2;
                    prev = c2;
                }
            }
            // compact from full z
            #pragma unroll
            for (int jj = 0; jj < 32; ++jj) {
                const float p = z[jj] - tau;
                if (p > 0.f) {
                    const int k = 4 * lh + 128 * (jj >> 2) + (jj & 3);
                    const int pos = atomicAdd(&cnt[qrow], 1);
                    list[qrow * 1024 + pos] = (unsigned int)k | ((unsigned int)bf16_of(p) << 16);
                }
            }
        } else {
            // ---- fast path: Michelot on <=4 candidate registers ----
            if (fullrow_masked) {
                tau = 3e38f;
            } else {
                tau = thr;
                unsigned prev = 0xFFFFFFFFu;
                for (int it = 0; it < 64; ++it) {
                    float s2 = 0.f; unsigned c2 = 0u;
                    s2 += (cv0 > tau) ? cv0 : 0.f;  c2 += (cv0 > tau) ? 1u : 0u;
                    s2 += (cv1 > tau) ? cv1 : 0.f;  c2 += (cv1 > tau) ? 1u : 0u;
                    s2 += (cv2 > tau) ? cv2 : 0.f;  c2 += (cv2 > tau) ? 1u : 0u;
                    s2 += (cv3 > tau) ? cv3 : 0.f;  c2 += (cv3 > tau) ? 1u : 0u;
                    #pragma unroll
                    for (int mm = 2; mm < 64; mm <<= 1) {
                        s2 += __shfl_xor(s2, mm);
                        c2 += __shfl_xor(c2, mm);
                    }
                    if (c2 == prev) break;
                    tau = (s2 - 1.f) / (float)c2;
                    prev = c2;
                }
            }
            // compact from candidate registers
            {
                float p;
                p = cv0 - tau;
                if (p > 0.f) { const int pos = atomicAdd(&cnt[qrow], 1);
                    list[qrow * 1024 + pos] = (unsigned int)ck0 | ((unsigned int)bf16_of(p) << 16); }
                p = cv1 - tau;
                if (p > 0.f) { const int pos = atomicAdd(&cnt[qrow], 1);
                    list[qrow * 1024 + pos] = (unsigned int)ck1 | ((unsigned int)bf16_of(p) << 16); }
                p = cv2 - tau;
                if (p > 0.f) { const int pos = atomicAdd(&cnt[qrow], 1);
                    list[qrow * 1024 + pos] = (unsigned int)ck2 | ((unsigned int)bf16_of(p) << 16); }
                p = cv3 - tau;
                if (p > 0.f) { const int pos = atomicAdd(&cnt[qrow], 1);
                    list[qrow * 1024 + pos] = (unsigned int)ck3 | ((unsigned int)bf16_of(p) << 16); }
            }
        }
        // same-wave RAW on cnt/list -> no barrier

        // ---- sparse PV (unroll x2): half-wave = row, lane = e-quad ----
        const float gsel = sel[b * 8 + h];
        const int n = cnt[prow];
        const ushort_t* Vrow = Vb + base;
        const unsigned int* lrow = list + prow * 1024;
        float a0 = 0.f, a1 = 0.f, a2 = 0.f, a3 = 0.f;
        float b0 = 0.f, b1 = 0.f, b2 = 0.f, b3 = 0.f;
        int j = 0;
        for (; j + 2 <= n; j += 2) {
            const unsigned int e0 = lrow[j];
            const unsigned int e1 = lrow[j + 1];
            const int k0 = (int)(e0 & 0xFFFFu);
            const int k1 = (int)(e1 & 0xFFFFu);
            const float g0 = gsel * f_of_bf16(e0 >> 16);
            const float g1 = gsel * f_of_bf16(e1 >> 16);
            us4 v0 = *reinterpret_cast<const us4*>(Vrow + (size_t)k0 * 128 + eq * 4);
            us4 v1 = *reinterpret_cast<const us4*>(Vrow + (size_t)k1 * 128 + eq * 4);
            a0 += g0 * f_of_bf16(v0.x); a1 += g0 * f_of_bf16(v0.y);
            a2 += g0 * f_of_bf16(v0.z); a3 += g0 * f_of_bf16(v0.w);
            b0 += g1 * f_of_bf16(v1.x); b1 += g1 * f_of_bf16(v1.y);
            b2 += g1 * f_of_bf16(v1.z); b3 += g1 * f_of_bf16(v1.w);
        }
        if (j < n) {
            const unsigned int e0 = lrow[j];
            const int k0 = (int)(e0 & 0xFFFFu);
            const float g0 = gsel * f_of_bf16(e0 >> 16);
            us4 v0 = *reinterpret_cast<const us4*>(Vrow + (size_t)k0 * 128 + eq * 4);
            a0 += g0 * f_of_bf16(v0.x); a1 += g0 * f_of_bf16(v0.y);
            a2 += g0 * f_of_bf16(v0.z); a3 += g0 * f_of_bf16(v0.w);
        }
        oac[0] += a0 + b0; oac[1] += a1 + b1;
        oac[2] += a2 + b2; oac[3] += a3 + b3;

        if (eq == 0) cnt[prow] = 0;   // reset by owning half-wave (in-order after reads)
    }

    // ---- single plain store (no atomics, every element covered exactly once) ----
    float* orow = out + ((size_t)(b * 1024 + t0 + prow)) * 128 + eq * 4;
    *reinterpret_cast<float4*>(orow) = (float4){oac[0], oac[1], oac[2], oac[3]};
}

extern "C" void kernel_launch(void* const* d_in, const int* in_sizes, int n_in,
                              void* d_out, int out_size, void* d_ws, size_t ws_size,
                              hipStream_t stream) {
    (void)in_sizes; (void)n_in; (void)ws_size; (void)out_size;
    const float* x   = (const float*)d_in[0];
    const int* mask  = (const int*)d_in[1];
    const float* wq  = (const float*)d_in[2];
    const float* wk  = (const float*)d_in[3];
    const float* wv  = (const float*)d_in[4];
    const float* wsl = (const float*)d_in[5];
    const float* bsl = (const float*)d_in[6];
    float* out = (float*)d_out;

    // ws layout: sel 1KB @0 | xsum 4KB @1024 | pad | mp 1MB @8192
    //            | xb 2MB | Wt 768KB | Q 16MB | K 16MB | V 16MB
    char* wsc = (char*)d_ws;
    float*    sel  = (float*)wsc;
    float*    xsum = (float*)(wsc + 1024);
    u64*      mp   = (u64*)(wsc + 8192);
    ushort_t* xb   = (ushort_t*)(wsc + 8192 + 1048576);
    ushort_t* Wt   = (ushort_t*)(wsc + 8192 + 1048576 + 2097152);
    ushort_t* Qb   = (ushort_t*)(wsc + 8192 + 1048576 + 2097152 + 786432);
    ushort_t* Kb   = Qb + (size_t)8388608;
    ushort_t* Vb   = Kb + (size_t)8388608;

    hipMemsetAsync(xsum, 0, 4096, stream);
    prep_all<<<3120, 256, 0, stream>>>(x, xb, wq, wk, wv, Wt, mask, mp, xsum);
    proj_gemm<<<dim3(128, 48), 256, 0, stream>>>(xb, Wt, Qb, Kb, Vb);
    sel_final<<<8, 128, 0, stream>>>(xsum, wsl, bsl, sel);
    attn_kernel<<<512, 512, 0, stream>>>(Qb, Kb, Vb, mp, sel, out);
}

// Round 14
// 279.175 us; speedup vs baseline: 1.3368x; 1.0433x over previous
//
#include <hip/hip_runtime.h>
#include <hip/hip_bf16.h>
#include <math.h>

#define SCALE 0.08838834764831845f  // 1/sqrt(128)

using short8  = __attribute__((ext_vector_type(8))) short;
using short4v = __attribute__((ext_vector_type(4))) short;
using us4     = __attribute__((ext_vector_type(4))) unsigned short;
using f32x4   = __attribute__((ext_vector_type(4))) float;
typedef unsigned long long u64;
typedef unsigned short ushort_t;

static __device__ __forceinline__ ushort_t bf16_of(float f) {
    __hip_bfloat16 h = __float2bfloat16(f);
    return *reinterpret_cast<ushort_t*>(&h);
}
static __device__ __forceinline__ float f_of_bf16(unsigned int u) {
    union { unsigned int i; float f; } v; v.i = u << 16; return v.f;
}
static __device__ __forceinline__ int mbcnt64(u64 m) {
    return __builtin_amdgcn_mbcnt_hi((unsigned)(m >> 32),
           __builtin_amdgcn_mbcnt_lo((unsigned)m, 0));
}

// ---------------- fused prep kernel ----------------
// grid 3120 x 256:
//   [0,1024)    : x -> bf16, plus column partial-sums into xsum[b][e]
//   [1024,1072) : W -> bf16 transposed [3072][128]
//   [1072,3120) : mask bit-pack (8192 rows x 16 u64)
__global__ __launch_bounds__(256)
void prep_all(const float* __restrict__ x, ushort_t* __restrict__ xb,
              const float* __restrict__ wq, const float* __restrict__ wk,
              const float* __restrict__ wv, ushort_t* __restrict__ Wt,
              const int* __restrict__ mask, u64* __restrict__ mp,
              float* __restrict__ xsum) {
    __shared__ float tile[64][129];
    __shared__ float csum[128];
    const int bx = blockIdx.x;
    const int tid = threadIdx.x;
    if (bx < 1024) {
        const int i = bx * 256 + tid;
        float4 v = reinterpret_cast<const float4*>(x)[i];
        short4v o;
        o.x = (short)bf16_of(v.x); o.y = (short)bf16_of(v.y);
        o.z = (short)bf16_of(v.z); o.w = (short)bf16_of(v.w);
        reinterpret_cast<short4v*>(xb)[i] = o;
        if (tid < 128) csum[tid] = 0.f;
        __syncthreads();
        const int e0 = (tid & 31) * 4;
        atomicAdd(&csum[e0 + 0], v.x);
        atomicAdd(&csum[e0 + 1], v.y);
        atomicAdd(&csum[e0 + 2], v.z);
        atomicAdd(&csum[e0 + 3], v.w);
        __syncthreads();
        if (tid < 128) atomicAdd(&xsum[(bx >> 7) * 128 + tid], csum[tid]);
    } else if (bx < 1072) {
        const int wb = bx - 1024;
        const int mat = wb >> 4;
        const int n0 = (wb & 15) * 64;
        const float* W = (mat == 0) ? wq : (mat == 1) ? wk : wv;
        for (int idx = tid; idx < 8192; idx += 256) {
            const int k = idx >> 6, c = idx & 63;
            tile[c][k] = W[(size_t)k * 1024 + n0 + c];
        }
        __syncthreads();
        for (int idx = tid; idx < 8192; idx += 256) {
            const int c = idx >> 7, k = idx & 127;
            Wt[(size_t)(mat * 1024 + n0 + c) * 128 + k] = bf16_of(tile[c][k]);
        }
    } else {
        const int mb = bx - 1072;
        const int row = mb * 4 + (tid >> 6);
        const int l = tid & 63;
        const int* m = mask + (size_t)row * 1024;
        #pragma unroll
        for (int c = 0; c < 16; ++c) {
            u64 bm = __ballot(m[c * 64 + l] != 0);
            if (l == 0) mp[(size_t)row * 16 + c] = bm;
        }
    }
}

// ---------------- MFMA projection GEMM ----------------
__global__ __launch_bounds__(256)
void proj_gemm(const ushort_t* __restrict__ xb, const ushort_t* __restrict__ Wt,
               ushort_t* __restrict__ Q, ushort_t* __restrict__ K,
               ushort_t* __restrict__ V) {
    const int tid = threadIdx.x;
    const int w = tid >> 6, l = tid & 63;
    const int l15 = l & 15, lq = l >> 4;
    const int m0 = blockIdx.x * 64;
    const int nb = blockIdx.y;
    const int mat = nb >> 4;
    const int n0 = (nb & 15) * 64;
    const int b = m0 >> 10;

    short8 af[4][4];
    #pragma unroll
    for (int at = 0; at < 4; ++at) {
        const ushort_t* ar = xb + (size_t)(m0 + at * 16 + l15) * 128 + lq * 8;
        #pragma unroll
        for (int f = 0; f < 4; ++f)
            af[at][f] = *reinterpret_cast<const short8*>(ar + f * 32);
    }
    const int ng = n0 + w * 16 + l15;
    const ushort_t* br = Wt + (size_t)(mat * 1024 + ng) * 128 + lq * 8;
    short8 bf[4];
    #pragma unroll
    for (int f = 0; f < 4; ++f)
        bf[f] = *reinterpret_cast<const short8*>(br + f * 32);
    f32x4 acc[4];
    #pragma unroll
    for (int at = 0; at < 4; ++at) acc[at] = (f32x4){0.f, 0.f, 0.f, 0.f};
    #pragma unroll
    for (int at = 0; at < 4; ++at)
        #pragma unroll
        for (int f = 0; f < 4; ++f)
            acc[at] = __builtin_amdgcn_mfma_f32_16x16x32_bf16(af[at][f], bf[f], acc[at], 0, 0, 0);

    const int h = ng >> 7, e = ng & 127;
    ushort_t* O = (mat == 0) ? Q : (mat == 1) ? K : V;
    const float scl = (mat == 0) ? SCALE : 1.0f;
    const size_t obase = (size_t)(h * 8 + b) * 131072 + e;
    #pragma unroll
    for (int at = 0; at < 4; ++at)
        #pragma unroll
        for (int r = 0; r < 4; ++r) {
            const int t = (m0 & 1023) + at * 16 + lq * 4 + r;
            O[obase + (size_t)t * 128] = bf16_of(acc[at][r] * scl);
        }
}

// ---------------- sel finalize (tiny) ----------------
__global__ __launch_bounds__(128)
void sel_final(const float* __restrict__ xsum, const float* __restrict__ wsl,
               const float* __restrict__ bsl, float* __restrict__ sel) {
    __shared__ float xm[128];
    __shared__ float lg[8];
    const int b = blockIdx.x;
    const int tid = threadIdx.x;
    xm[tid] = xsum[b * 128 + tid] * (1.0f / 1024.0f);
    __syncthreads();
    if (tid < 8) {
        float d = 0.f;
        for (int e = 0; e < 128; ++e) d += xm[e] * wsl[tid * 128 + e];
        lg[tid] = d + bsl[tid];
    }
    __syncthreads();
    if (tid == 0) {
        float mx = lg[0];
        for (int hh = 1; hh < 8; ++hh) mx = fmaxf(mx, lg[hh]);
        float se = 0.f; float ex[8];
        for (int hh = 0; hh < 8; ++hh) { ex[hh] = expf(lg[hh] - mx); se += ex[hh]; }
        for (int hh = 0; hh < 8; ++hh) sel[b * 8 + hh] = ex[hh] / se;
    }
}

// ---------------- MFMA attention: r8 structure + ballot compaction + hoisting ------
// grid 512 = 8 batches * 64 q-tiles; block 512 (8 waves); head loop inside.
// XCD x owns batch b=x (L2-resident per-head K/Q/V, ~2 heads in flight).
__global__ __launch_bounds__(512, 4)
void attn_kernel(const ushort_t* __restrict__ Qb, const ushort_t* __restrict__ Kb,
                 const ushort_t* __restrict__ Vb, const u64* __restrict__ mp,
                 const float* __restrict__ sel, float* __restrict__ out) {
    __shared__ float S[16 * 1024];   // 64 KB; support list aliases it
    unsigned int* list = reinterpret_cast<unsigned int*>(S);

    const int tid = threadIdx.x;
    const int w = tid >> 6, l = tid & 63;
    const int l15 = l & 15, lq = l >> 4;
    const int orig = (int)blockIdx.x;
    const int swz = (orig & 7) * 64 + (orig >> 3);   // XCD-chunked remap (512 % 8 == 0)
    const int b = swz >> 6;                          // batch locked to XCD
    const int qt = swz & 63;
    const int t0 = qt * 16;
    const int rowbase = b * 1024 + t0;

    const int qrow = 2 * w + (l & 1);   // row for transpose/solve/compact (parity)
    const int lh = l >> 1;
    const int prow = tid >> 5;          // row for PV (same wave's rows)
    const int eq = tid & 31;

    // ---- head-invariant precomputes ----
    // packed mask bits: mb[r] bit i == mask bit for sc[i][r]
    unsigned mb[4];
    #pragma unroll
    for (int r = 0; r < 4; ++r) {
        const u64* mrow = mp + (size_t)(rowbase + lq * 4 + r) * 16 + w * 2;
        const u64 m0 = mrow[0], m1 = mrow[1];
        unsigned acc = 0;
        #pragma unroll
        for (int i = 0; i < 8; ++i) {
            const u64 mword = (i < 4) ? m0 : m1;
            const int bit = (i & 3) * 16 + l15;
            acc |= (unsigned)((mword >> bit) & 1ULL) << i;
        }
        mb[r] = acc;
    }
    // store-swizzle bases (r-independent part): cbase[i] = c ^ ((c>>3)&7)
    int cbase[8];
    #pragma unroll
    for (int i = 0; i < 8; ++i) {
        const int c = (w * 8 + i) * 4 + (l15 >> 2);
        cbase[i] = c ^ ((c >> 3) & 7);
    }
    const int slo = l15 & 3;
    // transpose-read offsets
    int toff[8];
    #pragma unroll
    for (int j = 0; j < 8; ++j) {
        const int c = lh + 32 * j;
        toff[j] = qrow * 1024 + (c ^ ((c >> 3) & 7) ^ (qrow & 7)) * 4;
    }
    // per-head base pointers (head stride = 8*131072 elements)
    const ushort_t* Qp = Qb + (size_t)b * 131072;
    const ushort_t* Kp = Kb + (size_t)b * 131072;
    const ushort_t* Vp = Vb + (size_t)b * 131072;
    const int qoff = (t0 + l15) * 128 + lq * 8;
    const int koff = w * 16384 + l15 * 128 + lq * 8;

    const u64 PM_EVEN = 0x5555555555555555ULL;
    const u64 pmask = (l & 1) ? ~PM_EVEN : PM_EVEN;

    f32x4 oac = {0.f, 0.f, 0.f, 0.f};   // gated head-sum accumulator (prow, eq*4..+3)

    for (int h = 0; h < 8; ++h) {
        __syncthreads();   // prev head's list reads done before S overwrite

        // ---- Q A-frags ----
        short8 qa[4];
        {
            const ushort_t* qrp = Qp + qoff;
            #pragma unroll
            for (int f = 0; f < 4; ++f)
                qa[f] = *reinterpret_cast<const short8*>(qrp + f * 32);
        }

        // ---- QK^T: sc[i][r] = S[q=lq*4+r][k=(w*8+i)*16+l15] ----
        f32x4 sc[8];
        #pragma unroll
        for (int i = 0; i < 8; ++i) {
            const ushort_t* krow = Kp + koff + i * 2048;
            f32x4 acc = {0.f, 0.f, 0.f, 0.f};
            #pragma unroll
            for (int f = 0; f < 4; ++f) {
                short8 kb = *reinterpret_cast<const short8*>(krow + f * 32);
                acc = __builtin_amdgcn_mfma_f32_16x16x32_bf16(qa[f], kb, acc, 0, 0, 0);
            }
            sc[i] = acc;
        }

        // ---- mask (packed bits; bit=1 -> -1e30) ----
        #pragma unroll
        for (int r = 0; r < 4; ++r) {
            #pragma unroll
            for (int i = 0; i < 8; ++i) {
                if (mb[r] & (1u << i)) sc[i][r] = -1e30f;
            }
        }

        // ---- S store (f32, chunk-swizzled via cbase) ----
        #pragma unroll
        for (int r = 0; r < 4; ++r) {
            const int q = lq * 4 + r;
            const int qx = q & 7;
            #pragma unroll
            for (int i = 0; i < 8; ++i) {
                S[q * 1024 + (cbase[i] ^ qx) * 4 + slo] = sc[i][r];
            }
        }
        __syncthreads();

        // ---- transpose read: lane owns 32 vals of row qrow; z[4j+m] = col 4*lh+128*j+m ----
        float z[32];
        #pragma unroll
        for (int j = 0; j < 8; ++j) {
            float4 v = *reinterpret_cast<const float4*>(&S[toff[j]]);
            z[4 * j + 0] = v.x; z[4 * j + 1] = v.y;
            z[4 * j + 2] = v.z; z[4 * j + 3] = v.w;
        }
        // rows are wave-private from here (solve/compact/PV touch only rows 2w,2w+1)

        // ---- row max (tree + 5 same-parity shfl) ----
        float m16[16];
        #pragma unroll
        for (int j = 0; j < 16; ++j) m16[j] = fmaxf(z[j], z[j + 16]);
        #pragma unroll
        for (int j = 0; j < 8; ++j) m16[j] = fmaxf(m16[j], m16[j + 8]);
        #pragma unroll
        for (int j = 0; j < 4; ++j) m16[j] = fmaxf(m16[j], m16[j + 4]);
        float mx = fmaxf(fmaxf(m16[0], m16[1]), fmaxf(m16[2], m16[3]));
        #pragma unroll
        for (int mm = 2; mm < 64; mm <<= 1) mx = fmaxf(mx, __shfl_xor(mx, mm));

        // ---- Michelot sparsemax, warm start from {z > mx-1} (r8-proven path) ----
        float tau;
        if (mx < -1e29f) {
            tau = 3e38f;               // fully-masked row -> zero output
        } else {
            tau = mx - 1.0f;
            unsigned prev = 0xFFFFFFFFu;
            for (int it = 0; it < 64; ++it) {
                float s2 = 0.f; unsigned c2 = 0u;
                #pragma unroll
                for (int k = 0; k < 32; ++k) {
                    const float zz = z[k];
                    s2 += (zz > tau) ? zz : 0.f;
                    c2 += (zz > tau) ? 1u : 0u;
                }
                #pragma unroll
                for (int mm = 2; mm < 64; mm <<= 1) {
                    s2 += __shfl_xor(s2, mm);
                    c2 += __shfl_xor(c2, mm);
                }
                if (c2 == prev) break;
                tau = (s2 - 1.f) / (float)c2;
                prev = c2;
            }
        }

        // ---- ballot/mbcnt compaction (no LDS atomics; counts in registers) ----
        int base0 = 0, base1 = 0;
        #pragma unroll
        for (int jj = 0; jj < 32; ++jj) {
            const float p = z[jj] - tau;
            const u64 bal = __ballot(p > 0.f);
            if (p > 0.f) {
                const int myb = (l & 1) ? base1 : base0;
                const int pos = myb + mbcnt64(bal & pmask);
                const int k = 4 * lh + 128 * (jj >> 2) + (jj & 3);
                list[qrow * 1024 + pos] = (unsigned)k | ((unsigned)bf16_of(p) << 16);
            }
            base0 += __builtin_popcountll(bal & PM_EVEN);
            base1 += __builtin_popcountll(bal & ~PM_EVEN);
        }
        // same-wave RAW on list -> no barrier

        // ---- sparse PV (unroll x4): half-wave = row, lane = e-quad ----
        const float gsel = sel[b * 8 + h];
        const int n = (l < 32) ? base0 : base1;   // count for row prow (wave-uniform pair)
        const ushort_t* Vrow = Vp;
        const unsigned int* lrow = list + prow * 1024;
        float a0 = 0.f, a1 = 0.f, a2 = 0.f, a3 = 0.f;
        float b0 = 0.f, b1 = 0.f, b2 = 0.f, b3 = 0.f;
        int j = 0;
        for (; j + 4 <= n; j += 4) {
            const unsigned int e0 = lrow[j];
            const unsigned int e1 = lrow[j + 1];
            const unsigned int e2 = lrow[j + 2];
            const unsigned int e3 = lrow[j + 3];
            const float g0 = gsel * f_of_bf16(e0 >> 16);
            const float g1 = gsel * f_of_bf16(e1 >> 16);
            const float g2 = gsel * f_of_bf16(e2 >> 16);
            const float g3 = gsel * f_of_bf16(e3 >> 16);
            us4 v0 = *reinterpret_cast<const us4*>(Vrow + (size_t)(e0 & 0xFFFFu) * 128 + eq * 4);
            us4 v1 = *reinterpret_cast<const us4*>(Vrow + (size_t)(e1 & 0xFFFFu) * 128 + eq * 4);
            us4 v2 = *reinterpret_cast<const us4*>(Vrow + (size_t)(e2 & 0xFFFFu) * 128 + eq * 4);
            us4 v3 = *reinterpret_cast<const us4*>(Vrow + (size_t)(e3 & 0xFFFFu) * 128 + eq * 4);
            a0 += g0 * f_of_bf16(v0.x); a1 += g0 * f_of_bf16(v0.y);
            a2 += g0 * f_of_bf16(v0.z); a3 += g0 * f_of_bf16(v0.w);
            b0 += g1 * f_of_bf16(v1.x); b1 += g1 * f_of_bf16(v1.y);
            b2 += g1 * f_of_bf16(v1.z); b3 += g1 * f_of_bf16(v1.w);
            a0 += g2 * f_of_bf16(v2.x); a1 += g2 * f_of_bf16(v2.y);
            a2 += g2 * f_of_bf16(v2.z); a3 += g2 * f_of_bf16(v2.w);
            b0 += g3 * f_of_bf16(v3.x); b1 += g3 * f_of_bf16(v3.y);
            b2 += g3 * f_of_bf16(v3.z); b3 += g3 * f_of_bf16(v3.w);
        }
        for (; j < n; ++j) {
            const unsigned int e0 = lrow[j];
            const float g0 = gsel * f_of_bf16(e0 >> 16);
            us4 v0 = *reinterpret_cast<const us4*>(Vrow + (size_t)(e0 & 0xFFFFu) * 128 + eq * 4);
            a0 += g0 * f_of_bf16(v0.x); a1 += g0 * f_of_bf16(v0.y);
            a2 += g0 * f_of_bf16(v0.z); a3 += g0 * f_of_bf16(v0.w);
        }
        oac[0] += a0 + b0; oac[1] += a1 + b1;
        oac[2] += a2 + b2; oac[3] += a3 + b3;

        // ---- advance per-head pointers (stride 8*131072 elements) ----
        Qp += 1048576; Kp += 1048576; Vp += 1048576;
    }

    // ---- single plain store (no atomics, every element covered exactly once) ----
    float* orow = out + ((size_t)(b * 1024 + t0 + prow)) * 128 + eq * 4;
    *reinterpret_cast<float4*>(orow) = (float4){oac[0], oac[1], oac[2], oac[3]};
}

extern "C" void kernel_launch(void* const* d_in, const int* in_sizes, int n_in,
                              void* d_out, int out_size, void* d_ws, size_t ws_size,
                              hipStream_t stream) {
    (void)in_sizes; (void)n_in; (void)ws_size; (void)out_size;
    const float* x   = (const float*)d_in[0];
    const int* mask  = (const int*)d_in[1];
    const float* wq  = (const float*)d_in[2];
    const float* wk  = (const float*)d_in[3];
    const float* wv  = (const float*)d_in[4];
    const float* wsl = (const float*)d_in[5];
    const float* bsl = (const float*)d_in[6];
    float* out = (float*)d_out;

    // ws layout: sel 1KB @0 | xsum 4KB @1024 | pad | mp 1MB @8192
    //            | xb 2MB | Wt 768KB | Q 16MB | K 16MB | V 16MB
    char* wsc = (char*)d_ws;
    float*    sel  = (float*)wsc;
    float*    xsum = (float*)(wsc + 1024);
    u64*      mp   = (u64*)(wsc + 8192);
    ushort_t* xb   = (ushort_t*)(wsc + 8192 + 1048576);
    ushort_t* Wt   = (ushort_t*)(wsc + 8192 + 1048576 + 2097152);
    ushort_t* Qb   = (ushort_t*)(wsc + 8192 + 1048576 + 2097152 + 786432);
    ushort_t* Kb   = Qb + (size_t)8388608;
    ushort_t* Vb   = Kb + (size_t)8388608;

    hipMemsetAsync(xsum, 0, 4096, stream);
    prep_all<<<3120, 256, 0, stream>>>(x, xb, wq, wk, wv, Wt, mask, mp, xsum);
    proj_gemm<<<dim3(128, 48), 256, 0, stream>>>(xb, Wt, Qb, Kb, Vb);
    sel_final<<<8, 128, 0, stream>>>(xsum, wsl, bsl, sel);
    attn_kernel<<<512, 512, 0, stream>>>(Qb, Kb, Vb, mp, sel, out);
}

// Round 15
// 274.681 us; speedup vs baseline: 1.3587x; 1.0164x over previous
//
#include <hip/hip_runtime.h>
#include <hip/hip_bf16.h>
#include <math.h>

#define SCALE 0.08838834764831845f  // 1/sqrt(128)

using short8  = __attribute__((ext_vector_type(8))) short;
using short4v = __attribute__((ext_vector_type(4))) short;
using us4     = __attribute__((ext_vector_type(4))) unsigned short;
using f32x4   = __attribute__((ext_vector_type(4))) float;
typedef unsigned long long u64;
typedef unsigned short ushort_t;

static __device__ __forceinline__ ushort_t bf16_of(float f) {
    __hip_bfloat16 h = __float2bfloat16(f);
    return *reinterpret_cast<ushort_t*>(&h);
}
static __device__ __forceinline__ float f_of_bf16(unsigned int u) {
    union { unsigned int i; float f; } v; v.i = u << 16; return v.f;
}

// ---------------- fused prep kernel ----------------
// grid 3120 x 256:
//   [0,1024)    : x -> bf16, plus column partial-sums into xsum[b][e]
//   [1024,1072) : W -> bf16 transposed [3072][128]
//   [1072,3120) : mask bit-pack (8192 rows x 16 u64)
__global__ __launch_bounds__(256)
void prep_all(const float* __restrict__ x, ushort_t* __restrict__ xb,
              const float* __restrict__ wq, const float* __restrict__ wk,
              const float* __restrict__ wv, ushort_t* __restrict__ Wt,
              const int* __restrict__ mask, u64* __restrict__ mp,
              float* __restrict__ xsum) {
    __shared__ float tile[64][129];
    __shared__ float csum[128];
    const int bx = blockIdx.x;
    const int tid = threadIdx.x;
    if (bx < 1024) {
        const int i = bx * 256 + tid;
        float4 v = reinterpret_cast<const float4*>(x)[i];
        short4v o;
        o.x = (short)bf16_of(v.x); o.y = (short)bf16_of(v.y);
        o.z = (short)bf16_of(v.z); o.w = (short)bf16_of(v.w);
        reinterpret_cast<short4v*>(xb)[i] = o;
        if (tid < 128) csum[tid] = 0.f;
        __syncthreads();
        const int e0 = (tid & 31) * 4;
        atomicAdd(&csum[e0 + 0], v.x);
        atomicAdd(&csum[e0 + 1], v.y);
        atomicAdd(&csum[e0 + 2], v.z);
        atomicAdd(&csum[e0 + 3], v.w);
        __syncthreads();
        if (tid < 128) atomicAdd(&xsum[(bx >> 7) * 128 + tid], csum[tid]);
    } else if (bx < 1072) {
        const int wb = bx - 1024;
        const int mat = wb >> 4;
        const int n0 = (wb & 15) * 64;
        const float* W = (mat == 0) ? wq : (mat == 1) ? wk : wv;
        for (int idx = tid; idx < 8192; idx += 256) {
            const int k = idx >> 6, c = idx & 63;
            tile[c][k] = W[(size_t)k * 1024 + n0 + c];
        }
        __syncthreads();
        for (int idx = tid; idx < 8192; idx += 256) {
            const int c = idx >> 7, k = idx & 127;
            Wt[(size_t)(mat * 1024 + n0 + c) * 128 + k] = bf16_of(tile[c][k]);
        }
    } else {
        const int mb = bx - 1072;
        const int row = mb * 4 + (tid >> 6);
        const int l = tid & 63;
        const int* m = mask + (size_t)row * 1024;
        #pragma unroll
        for (int c = 0; c < 16; ++c) {
            u64 bm = __ballot(m[c * 64 + l] != 0);
            if (l == 0) mp[(size_t)row * 16 + c] = bm;
        }
    }
}

// ---------------- MFMA projection GEMM ----------------
// grid (128, 48), block 256 (4 waves). mat = blockIdx.y>>4 (0 Q,1 K,2 V).
// All outputs row-major bf16 [hb][t][128]; Q pre-scaled.
__global__ __launch_bounds__(256)
void proj_gemm(const ushort_t* __restrict__ xb, const ushort_t* __restrict__ Wt,
               ushort_t* __restrict__ Q, ushort_t* __restrict__ K,
               ushort_t* __restrict__ V) {
    const int tid = threadIdx.x;
    const int w = tid >> 6, l = tid & 63;
    const int l15 = l & 15, lq = l >> 4;
    const int m0 = blockIdx.x * 64;
    const int nb = blockIdx.y;
    const int mat = nb >> 4;
    const int n0 = (nb & 15) * 64;
    const int b = m0 >> 10;

    short8 af[4][4];
    #pragma unroll
    for (int at = 0; at < 4; ++at) {
        const ushort_t* ar = xb + (size_t)(m0 + at * 16 + l15) * 128 + lq * 8;
        #pragma unroll
        for (int f = 0; f < 4; ++f)
            af[at][f] = *reinterpret_cast<const short8*>(ar + f * 32);
    }
    const int ng = n0 + w * 16 + l15;
    const ushort_t* br = Wt + (size_t)(mat * 1024 + ng) * 128 + lq * 8;
    short8 bf[4];
    #pragma unroll
    for (int f = 0; f < 4; ++f)
        bf[f] = *reinterpret_cast<const short8*>(br + f * 32);
    f32x4 acc[4];
    #pragma unroll
    for (int at = 0; at < 4; ++at) acc[at] = (f32x4){0.f, 0.f, 0.f, 0.f};
    #pragma unroll
    for (int at = 0; at < 4; ++at)
        #pragma unroll
        for (int f = 0; f < 4; ++f)
            acc[at] = __builtin_amdgcn_mfma_f32_16x16x32_bf16(af[at][f], bf[f], acc[at], 0, 0, 0);

    const int h = ng >> 7, e = ng & 127;
    ushort_t* O = (mat == 0) ? Q : (mat == 1) ? K : V;
    const float scl = (mat == 0) ? SCALE : 1.0f;
    const size_t obase = (size_t)(h * 8 + b) * 131072 + e;
    #pragma unroll
    for (int at = 0; at < 4; ++at)
        #pragma unroll
        for (int r = 0; r < 4; ++r) {
            const int t = (m0 & 1023) + at * 16 + lq * 4 + r;
            O[obase + (size_t)t * 128] = bf16_of(acc[at][r] * scl);
        }
}

// ---------------- sel finalize (tiny) ----------------
__global__ __launch_bounds__(128)
void sel_final(const float* __restrict__ xsum, const float* __restrict__ wsl,
               const float* __restrict__ bsl, float* __restrict__ sel) {
    __shared__ float xm[128];
    __shared__ float lg[8];
    const int b = blockIdx.x;
    const int tid = threadIdx.x;
    xm[tid] = xsum[b * 128 + tid] * (1.0f / 1024.0f);
    __syncthreads();
    if (tid < 8) {
        float d = 0.f;
        for (int e = 0; e < 128; ++e) d += xm[e] * wsl[tid * 128 + e];
        lg[tid] = d + bsl[tid];
    }
    __syncthreads();
    if (tid == 0) {
        float mx = lg[0];
        for (int hh = 1; hh < 8; ++hh) mx = fmaxf(mx, lg[hh]);
        float se = 0.f; float ex[8];
        for (int hh = 0; hh < 8; ++hh) { ex[hh] = expf(lg[hh] - mx); se += ex[hh]; }
        for (int hh = 0; hh < 8; ++hh) sel[b * 8 + hh] = ex[hh] / se;
    }
}

// ---------------- MFMA attention: round-8 proven kernel (verbatim) ----------------
// grid 512 = 8 batches * 64 q-tiles; block 512 (8 waves); head loop inside.
// XCD x owns batch b=x (L2-resident per-head K/Q/V, ~2 heads in flight).
__global__ __launch_bounds__(512, 4)
void attn_kernel(const ushort_t* __restrict__ Qb, const ushort_t* __restrict__ Kb,
                 const ushort_t* __restrict__ Vb, const u64* __restrict__ mp,
                 const float* __restrict__ sel, float* __restrict__ out) {
    __shared__ float S[16 * 1024];   // 64 KB; support list aliases it
    __shared__ int cnt[16];
    unsigned int* list = reinterpret_cast<unsigned int*>(S);

    const int tid = threadIdx.x;
    const int w = tid >> 6, l = tid & 63;
    const int l15 = l & 15, lq = l >> 4;
    const int orig = (int)blockIdx.x;
    const int swz = (orig & 7) * 64 + (orig >> 3);   // XCD-chunked remap (512 % 8 == 0)
    const int b = swz >> 6;                          // batch locked to XCD
    const int qt = swz & 63;
    const int t0 = qt * 16;
    const int rowbase = b * 1024 + t0;

    const int qrow = 2 * w + (l & 1);   // row for transpose/solve/compact (parity)
    const int lh = l >> 1;
    const int prow = tid >> 5;          // row for PV (same wave's rows)
    const int eq = tid & 31;

    if (tid < 16) cnt[tid] = 0;

    // ---- hoist head-invariant mask words: rows q=lq*4+r, words w*2, w*2+1 ----
    u64 mw0[4], mw1[4];
    #pragma unroll
    for (int r = 0; r < 4; ++r) {
        const u64* mrow = mp + (size_t)(rowbase + lq * 4 + r) * 16 + w * 2;
        mw0[r] = mrow[0];
        mw1[r] = mrow[1];
    }

    f32x4 oac = {0.f, 0.f, 0.f, 0.f};   // gated head-sum accumulator (prow, eq*4..+3)

    for (int h = 0; h < 8; ++h) {
        const size_t base = (size_t)(h * 8 + b) * 131072;
        __syncthreads();   // prev head's list reads done before S overwrite

        // ---- Q A-frags ----
        short8 qa[4];
        {
            const ushort_t* qrp = Qb + base + (size_t)(t0 + l15) * 128 + lq * 8;
            #pragma unroll
            for (int f = 0; f < 4; ++f)
                qa[f] = *reinterpret_cast<const short8*>(qrp + f * 32);
        }

        // ---- QK^T: sc[i][r] = S[q=lq*4+r][k=(w*8+i)*16+l15] ----
        f32x4 sc[8];
        #pragma unroll
        for (int i = 0; i < 8; ++i) {
            const int kt = w * 8 + i;
            const ushort_t* krow = Kb + base + (size_t)(kt * 16 + l15) * 128 + lq * 8;
            f32x4 acc = {0.f, 0.f, 0.f, 0.f};
            #pragma unroll
            for (int f = 0; f < 4; ++f) {
                short8 kb = *reinterpret_cast<const short8*>(krow + f * 32);
                acc = __builtin_amdgcn_mfma_f32_16x16x32_bf16(qa[f], kb, acc, 0, 0, 0);
            }
            sc[i] = acc;
        }

        // ---- mask (hoisted words; bit=1 -> -1e30) ----
        #pragma unroll
        for (int r = 0; r < 4; ++r) {
            #pragma unroll
            for (int i = 0; i < 8; ++i) {
                const u64 mword = (i < 4) ? mw0[r] : mw1[r];
                const int bit = (i & 3) * 16 + l15;
                if ((mword >> bit) & 1ULL) sc[i][r] = -1e30f;
            }
        }

        // ---- S store (f32, chunk-swizzled) ----
        #pragma unroll
        for (int r = 0; r < 4; ++r) {
            const int q = lq * 4 + r;
            #pragma unroll
            for (int i = 0; i < 8; ++i) {
                const int c = (w * 8 + i) * 4 + (l15 >> 2);
                const int cp = c ^ ((c >> 3) & 7) ^ (q & 7);
                S[q * 1024 + cp * 4 + (l15 & 3)] = sc[i][r];
            }
        }
        __syncthreads();

        // ---- transpose read: lane owns 32 vals of row qrow; z[4j+m] = col 4*lh+128*j+m ----
        float z[32];
        #pragma unroll
        for (int j = 0; j < 8; ++j) {
            const int c = lh + 32 * j;
            const int cp = c ^ ((c >> 3) & 7) ^ (qrow & 7);
            float4 v = *reinterpret_cast<const float4*>(&S[qrow * 1024 + cp * 4]);
            z[4 * j + 0] = v.x; z[4 * j + 1] = v.y;
            z[4 * j + 2] = v.z; z[4 * j + 3] = v.w;
        }
        // rows are wave-private from here (solve/compact/PV touch only rows 2w,2w+1)

        // ---- row max (tree + 5 same-parity shfl) ----
        float m16[16];
        #pragma unroll
        for (int j = 0; j < 16; ++j) m16[j] = fmaxf(z[j], z[j + 16]);
        #pragma unroll
        for (int j = 0; j < 8; ++j) m16[j] = fmaxf(m16[j], m16[j + 8]);
        #pragma unroll
        for (int j = 0; j < 4; ++j) m16[j] = fmaxf(m16[j], m16[j + 4]);
        float mx = fmaxf(fmaxf(m16[0], m16[1]), fmaxf(m16[2], m16[3]));
        #pragma unroll
        for (int mm = 2; mm < 64; mm <<= 1) mx = fmaxf(mx, __shfl_xor(mx, mm));

        // ---- Michelot sparsemax, warm start from {z > mx-1} (superset of support) ----
        float tau;
        if (mx < -1e29f) {
            tau = 3e38f;               // fully-masked row -> zero output
        } else {
            tau = mx - 1.0f;
            unsigned prev = 0xFFFFFFFFu;
            for (int it = 0; it < 64; ++it) {
                float s2 = 0.f; unsigned c2 = 0u;
                #pragma unroll
                for (int k = 0; k < 32; ++k) {
                    const float zz = z[k];
                    s2 += (zz > tau) ? zz : 0.f;
                    c2 += (zz > tau) ? 1u : 0u;
                }
                #pragma unroll
                for (int mm = 2; mm < 64; mm <<= 1) {
                    s2 += __shfl_xor(s2, mm);
                    c2 += __shfl_xor(c2, mm);
                }
                if (c2 == prev) break;
                tau = (s2 - 1.f) / (float)c2;
                prev = c2;
            }
        }

        // ---- compact support (k, p-bf16) into list rows 2w,2w+1 (wave-private) ----
        #pragma unroll
        for (int jj = 0; jj < 32; ++jj) {
            const float p = z[jj] - tau;
            if (p > 0.f) {
                const int k = 4 * lh + 128 * (jj >> 2) + (jj & 3);
                const int pos = atomicAdd(&cnt[qrow], 1);
                list[qrow * 1024 + pos] = (unsigned int)k | ((unsigned int)bf16_of(p) << 16);
            }
        }
        // same-wave RAW on cnt/list -> no barrier

        // ---- sparse PV: half-wave = row, lane = e-quad; oac += gsel * p * V[k] ----
        const float gsel = sel[b * 8 + h];
        const int n = cnt[prow];
        const ushort_t* Vrow = Vb + base;
        const unsigned int* lrow = list + prow * 1024;
        for (int j = 0; j < n; ++j) {
            const unsigned int ent = lrow[j];
            const int k = (int)(ent & 0xFFFFu);
            const float gp = gsel * f_of_bf16(ent >> 16);
            us4 vv = *reinterpret_cast<const us4*>(Vrow + (size_t)k * 128 + eq * 4);
            oac[0] += gp * f_of_bf16(vv.x);
            oac[1] += gp * f_of_bf16(vv.y);
            oac[2] += gp * f_of_bf16(vv.z);
            oac[3] += gp * f_of_bf16(vv.w);
        }
        if (eq == 0) cnt[prow] = 0;   // reset by owning half-wave (in-order after reads)
    }

    // ---- single plain store (no atomics, every element covered exactly once) ----
    float* orow = out + ((size_t)(b * 1024 + t0 + prow)) * 128 + eq * 4;
    *reinterpret_cast<float4*>(orow) = (float4){oac[0], oac[1], oac[2], oac[3]};
}

extern "C" void kernel_launch(void* const* d_in, const int* in_sizes, int n_in,
                              void* d_out, int out_size, void* d_ws, size_t ws_size,
                              hipStream_t stream) {
    (void)in_sizes; (void)n_in; (void)ws_size; (void)out_size;
    const float* x   = (const float*)d_in[0];
    const int* mask  = (const int*)d_in[1];
    const float* wq  = (const float*)d_in[2];
    const float* wk  = (const float*)d_in[3];
    const float* wv  = (const float*)d_in[4];
    const float* wsl = (const float*)d_in[5];
    const float* bsl = (const float*)d_in[6];
    float* out = (float*)d_out;

    // ws layout: sel 1KB @0 | xsum 4KB @1024 | pad | mp 1MB @8192
    //            | xb 2MB | Wt 768KB | Q 16MB | K 16MB | V 16MB
    char* wsc = (char*)d_ws;
    float*    sel  = (float*)wsc;
    float*    xsum = (float*)(wsc + 1024);
    u64*      mp   = (u64*)(wsc + 8192);
    ushort_t* xb   = (ushort_t*)(wsc + 8192 + 1048576);
    ushort_t* Wt   = (ushort_t*)(wsc + 8192 + 1048576 + 2097152);
    ushort_t* Qb   = (ushort_t*)(wsc + 8192 + 1048576 + 2097152 + 786432);
    ushort_t* Kb   = Qb + (size_t)8388608;
    ushort_t* Vb   = Kb + (size_t)8388608;

    hipMemsetAsync(xsum, 0, 4096, stream);
    prep_all<<<3120, 256, 0, stream>>>(x, xb, wq, wk, wv, Wt, mask, mp, xsum);
    proj_gemm<<<dim3(128, 48), 256, 0, stream>>>(xb, Wt, Qb, Kb, Vb);
    sel_final<<<8, 128, 0, stream>>>(xsum, wsl, bsl, sel);
    attn_kernel<<<512, 512, 0, stream>>>(Qb, Kb, Vb, mp, sel, out);
}

// Round 16
// 268.308 us; speedup vs baseline: 1.3910x; 1.0238x over previous
//
#include <hip/hip_runtime.h>
#include <hip/hip_bf16.h>
#include <math.h>

#define SCALE 0.08838834764831845f  // 1/sqrt(128)

using short8  = __attribute__((ext_vector_type(8))) short;
using short4v = __attribute__((ext_vector_type(4))) short;
using us4     = __attribute__((ext_vector_type(4))) unsigned short;
using f32x4   = __attribute__((ext_vector_type(4))) float;
typedef unsigned long long u64;
typedef unsigned short ushort_t;

static __device__ __forceinline__ ushort_t bf16_of(float f) {
    __hip_bfloat16 h = __float2bfloat16(f);
    return *reinterpret_cast<ushort_t*>(&h);
}
static __device__ __forceinline__ float f_of_bf16(unsigned int u) {
    union { unsigned int i; float f; } v; v.i = u << 16; return v.f;
}

// ---------------- fused prep kernel (r8 form: no xsum) ----------------
// grid 3120 x 256:
//   [0,1024)    : x -> bf16
//   [1024,1072) : W -> bf16 transposed [3072][128]
//   [1072,3120) : mask bit-pack (8192 rows x 16 u64)
__global__ __launch_bounds__(256)
void prep_all(const float* __restrict__ x, ushort_t* __restrict__ xb,
              const float* __restrict__ wq, const float* __restrict__ wk,
              const float* __restrict__ wv, ushort_t* __restrict__ Wt,
              const int* __restrict__ mask, u64* __restrict__ mp) {
    __shared__ float tile[64][129];
    const int bx = blockIdx.x;
    const int tid = threadIdx.x;
    if (bx < 1024) {
        const int i = bx * 256 + tid;
        float4 v = reinterpret_cast<const float4*>(x)[i];
        short4v o;
        o.x = (short)bf16_of(v.x); o.y = (short)bf16_of(v.y);
        o.z = (short)bf16_of(v.z); o.w = (short)bf16_of(v.w);
        reinterpret_cast<short4v*>(xb)[i] = o;
    } else if (bx < 1072) {
        const int wb = bx - 1024;
        const int mat = wb >> 4;
        const int n0 = (wb & 15) * 64;
        const float* W = (mat == 0) ? wq : (mat == 1) ? wk : wv;
        for (int idx = tid; idx < 8192; idx += 256) {
            const int k = idx >> 6, c = idx & 63;
            tile[c][k] = W[(size_t)k * 1024 + n0 + c];
        }
        __syncthreads();
        for (int idx = tid; idx < 8192; idx += 256) {
            const int c = idx >> 7, k = idx & 127;
            Wt[(size_t)(mat * 1024 + n0 + c) * 128 + k] = bf16_of(tile[c][k]);
        }
    } else {
        const int mb = bx - 1072;
        const int row = mb * 4 + (tid >> 6);
        const int l = tid & 63;
        const int* m = mask + (size_t)row * 1024;
        #pragma unroll
        for (int c = 0; c < 16; ++c) {
            u64 bm = __ballot(m[c * 64 + l] != 0);
            if (l == 0) mp[(size_t)row * 16 + c] = bm;
        }
    }
}

// ---------------- MFMA projection GEMM ----------------
// grid (128, 48), block 256 (4 waves). mat = blockIdx.y>>4 (0 Q,1 K,2 V).
// All outputs row-major bf16 [hb][t][128]; Q pre-scaled.
__global__ __launch_bounds__(256)
void proj_gemm(const ushort_t* __restrict__ xb, const ushort_t* __restrict__ Wt,
               ushort_t* __restrict__ Q, ushort_t* __restrict__ K,
               ushort_t* __restrict__ V) {
    const int tid = threadIdx.x;
    const int w = tid >> 6, l = tid & 63;
    const int l15 = l & 15, lq = l >> 4;
    const int m0 = blockIdx.x * 64;
    const int nb = blockIdx.y;
    const int mat = nb >> 4;
    const int n0 = (nb & 15) * 64;
    const int b = m0 >> 10;

    short8 af[4][4];
    #pragma unroll
    for (int at = 0; at < 4; ++at) {
        const ushort_t* ar = xb + (size_t)(m0 + at * 16 + l15) * 128 + lq * 8;
        #pragma unroll
        for (int f = 0; f < 4; ++f)
            af[at][f] = *reinterpret_cast<const short8*>(ar + f * 32);
    }
    const int ng = n0 + w * 16 + l15;
    const ushort_t* br = Wt + (size_t)(mat * 1024 + ng) * 128 + lq * 8;
    short8 bf[4];
    #pragma unroll
    for (int f = 0; f < 4; ++f)
        bf[f] = *reinterpret_cast<const short8*>(br + f * 32);
    f32x4 acc[4];
    #pragma unroll
    for (int at = 0; at < 4; ++at) acc[at] = (f32x4){0.f, 0.f, 0.f, 0.f};
    #pragma unroll
    for (int at = 0; at < 4; ++at)
        #pragma unroll
        for (int f = 0; f < 4; ++f)
            acc[at] = __builtin_amdgcn_mfma_f32_16x16x32_bf16(af[at][f], bf[f], acc[at], 0, 0, 0);

    const int h = ng >> 7, e = ng & 127;
    ushort_t* O = (mat == 0) ? Q : (mat == 1) ? K : V;
    const float scl = (mat == 0) ? SCALE : 1.0f;
    const size_t obase = (size_t)(h * 8 + b) * 131072 + e;
    #pragma unroll
    for (int at = 0; at < 4; ++at)
        #pragma unroll
        for (int r = 0; r < 4; ++r) {
            const int t = (m0 & 1023) + at * 16 + lq * 4 + r;
            O[obase + (size_t)t * 128] = bf16_of(acc[at][r] * scl);
        }
}

// ---------------- gating (sel) kernel (r8 form) ----------------
__global__ __launch_bounds__(1024)
void sel_kernel(const float* __restrict__ x, const float* __restrict__ wsl,
                const float* __restrict__ bsl, float* __restrict__ sel) {
    __shared__ float part[8][128];
    __shared__ float xm[128];
    __shared__ float lg[8];
    const int b = blockIdx.x;
    const int tid = threadIdx.x;
    const int e = tid & 127, tc = tid >> 7;
    float s = 0.f;
    for (int t = 0; t < 128; ++t)
        s += x[((size_t)b * 1024 + tc * 128 + t) * 128 + e];
    part[tc][e] = s;
    __syncthreads();
    if (tid < 128) {
        float tot = 0.f;
        #pragma unroll
        for (int i = 0; i < 8; ++i) tot += part[i][tid];
        xm[tid] = tot * (1.0f / 1024.0f);
    }
    __syncthreads();
    if (tid < 8) {
        float d = 0.f;
        for (int e2 = 0; e2 < 128; ++e2) d += xm[e2] * wsl[tid * 128 + e2];
        lg[tid] = d + bsl[tid];
    }
    __syncthreads();
    if (tid == 0) {
        float mx = lg[0];
        for (int hh = 1; hh < 8; ++hh) mx = fmaxf(mx, lg[hh]);
        float se = 0.f; float ex[8];
        for (int hh = 0; hh < 8; ++hh) { ex[hh] = expf(lg[hh] - mx); se += ex[hh]; }
        for (int hh = 0; hh < 8; ++hh) sel[b * 8 + hh] = ex[hh] / se;
    }
}

// ---------------- MFMA attention: round-8 proven kernel ----------------
// grid 512 = 8 batches * 64 q-tiles; block 512 (8 waves); head loop inside.
// XCD x owns batch b=x (L2-resident per-head K/Q/V, ~2 heads in flight).
__global__ __launch_bounds__(512, 4)
void attn_kernel(const ushort_t* __restrict__ Qb, const ushort_t* __restrict__ Kb,
                 const ushort_t* __restrict__ Vb, const u64* __restrict__ mp,
                 const float* __restrict__ sel, float* __restrict__ out) {
    __shared__ float S[16 * 1024];   // 64 KB; support list aliases it
    __shared__ int cnt[16];
    unsigned int* list = reinterpret_cast<unsigned int*>(S);

    const int tid = threadIdx.x;
    const int w = tid >> 6, l = tid & 63;
    const int l15 = l & 15, lq = l >> 4;
    const int orig = (int)blockIdx.x;
    const int swz = (orig & 7) * 64 + (orig >> 3);   // XCD-chunked remap (512 % 8 == 0)
    const int b = swz >> 6;                          // batch locked to XCD
    const int qt = swz & 63;
    const int t0 = qt * 16;
    const int rowbase = b * 1024 + t0;

    const int qrow = 2 * w + (l & 1);   // row for transpose/solve/compact (parity)
    const int lh = l >> 1;
    const int prow = tid >> 5;          // row for PV (same wave's rows)
    const int eq = tid & 31;

    if (tid < 16) cnt[tid] = 0;

    // ---- hoist head-invariant mask words: rows q=lq*4+r, words w*2, w*2+1 ----
    u64 mw0[4], mw1[4];
    #pragma unroll
    for (int r = 0; r < 4; ++r) {
        const u64* mrow = mp + (size_t)(rowbase + lq * 4 + r) * 16 + w * 2;
        mw0[r] = mrow[0];
        mw1[r] = mrow[1];
    }

    f32x4 oac = {0.f, 0.f, 0.f, 0.f};   // gated head-sum accumulator (prow, eq*4..+3)

    for (int h = 0; h < 8; ++h) {
        const size_t base = (size_t)(h * 8 + b) * 131072;
        __syncthreads();   // prev head's list reads done before S overwrite

        // ---- Q A-frags ----
        short8 qa[4];
        {
            const ushort_t* qrp = Qb + base + (size_t)(t0 + l15) * 128 + lq * 8;
            #pragma unroll
            for (int f = 0; f < 4; ++f)
                qa[f] = *reinterpret_cast<const short8*>(qrp + f * 32);
        }

        // ---- QK^T: sc[i][r] = S[q=lq*4+r][k=(w*8+i)*16+l15] ----
        f32x4 sc[8];
        #pragma unroll
        for (int i = 0; i < 8; ++i) {
            const int kt = w * 8 + i;
            const ushort_t* krow = Kb + base + (size_t)(kt * 16 + l15) * 128 + lq * 8;
            f32x4 acc = {0.f, 0.f, 0.f, 0.f};
            #pragma unroll
            for (int f = 0; f < 4; ++f) {
                short8 kb = *reinterpret_cast<const short8*>(krow + f * 32);
                acc = __builtin_amdgcn_mfma_f32_16x16x32_bf16(qa[f], kb, acc, 0, 0, 0);
            }
            sc[i] = acc;
        }

        // ---- mask (hoisted words; bit=1 -> -1e30) ----
        #pragma unroll
        for (int r = 0; r < 4; ++r) {
            #pragma unroll
            for (int i = 0; i < 8; ++i) {
                const u64 mword = (i < 4) ? mw0[r] : mw1[r];
                const int bit = (i & 3) * 16 + l15;
                if ((mword >> bit) & 1ULL) sc[i][r] = -1e30f;
            }
        }

        // ---- S store (f32, chunk-swizzled) ----
        #pragma unroll
        for (int r = 0; r < 4; ++r) {
            const int q = lq * 4 + r;
            #pragma unroll
            for (int i = 0; i < 8; ++i) {
                const int c = (w * 8 + i) * 4 + (l15 >> 2);
                const int cp = c ^ ((c >> 3) & 7) ^ (q & 7);
                S[q * 1024 + cp * 4 + (l15 & 3)] = sc[i][r];
            }
        }
        __syncthreads();

        // ---- transpose read: lane owns 32 vals of row qrow; z[4j+m] = col 4*lh+128*j+m ----
        float z[32];
        #pragma unroll
        for (int j = 0; j < 8; ++j) {
            const int c = lh + 32 * j;
            const int cp = c ^ ((c >> 3) & 7) ^ (qrow & 7);
            float4 v = *reinterpret_cast<const float4*>(&S[qrow * 1024 + cp * 4]);
            z[4 * j + 0] = v.x; z[4 * j + 1] = v.y;
            z[4 * j + 2] = v.z; z[4 * j + 3] = v.w;
        }
        // rows are wave-private from here (solve/compact/PV touch only rows 2w,2w+1)

        // ---- row max (tree + 5 same-parity shfl) ----
        float m16[16];
        #pragma unroll
        for (int j = 0; j < 16; ++j) m16[j] = fmaxf(z[j], z[j + 16]);
        #pragma unroll
        for (int j = 0; j < 8; ++j) m16[j] = fmaxf(m16[j], m16[j + 8]);
        #pragma unroll
        for (int j = 0; j < 4; ++j) m16[j] = fmaxf(m16[j], m16[j + 4]);
        float mx = fmaxf(fmaxf(m16[0], m16[1]), fmaxf(m16[2], m16[3]));
        #pragma unroll
        for (int mm = 2; mm < 64; mm <<= 1) mx = fmaxf(mx, __shfl_xor(mx, mm));

        // ---- Michelot sparsemax, warm start from {z > mx-1} (superset of support) ----
        float tau;
        if (mx < -1e29f) {
            tau = 3e38f;               // fully-masked row -> zero output
        } else {
            tau = mx - 1.0f;
            unsigned prev = 0xFFFFFFFFu;
            for (int it = 0; it < 64; ++it) {
                float s2 = 0.f; unsigned c2 = 0u;
                #pragma unroll
                for (int k = 0; k < 32; ++k) {
                    const float zz = z[k];
                    s2 += (zz > tau) ? zz : 0.f;
                    c2 += (zz > tau) ? 1u : 0u;
                }
                #pragma unroll
                for (int mm = 2; mm < 64; mm <<= 1) {
                    s2 += __shfl_xor(s2, mm);
                    c2 += __shfl_xor(c2, mm);
                }
                if (c2 == prev) break;
                tau = (s2 - 1.f) / (float)c2;
                prev = c2;
            }
        }

        // ---- compact support (k, p-bf16) into list rows 2w,2w+1 (wave-private) ----
        #pragma unroll
        for (int jj = 0; jj < 32; ++jj) {
            const float p = z[jj] - tau;
            if (p > 0.f) {
                const int k = 4 * lh + 128 * (jj >> 2) + (jj & 3);
                const int pos = atomicAdd(&cnt[qrow], 1);
                list[qrow * 1024 + pos] = (unsigned int)k | ((unsigned int)bf16_of(p) << 16);
            }
        }
        // same-wave RAW on cnt/list -> no barrier

        // ---- sparse PV: half-wave = row, lane = e-quad; oac += gsel * p * V[k] ----
        const float gsel = sel[b * 8 + h];
        const int n = cnt[prow];
        const ushort_t* Vrow = Vb + base;
        const unsigned int* lrow = list + prow * 1024;
        for (int j = 0; j < n; ++j) {
            const unsigned int ent = lrow[j];
            const int k = (int)(ent & 0xFFFFu);
            const float gp = gsel * f_of_bf16(ent >> 16);
            us4 vv = *reinterpret_cast<const us4*>(Vrow + (size_t)k * 128 + eq * 4);
            oac[0] += gp * f_of_bf16(vv.x);
            oac[1] += gp * f_of_bf16(vv.y);
            oac[2] += gp * f_of_bf16(vv.z);
            oac[3] += gp * f_of_bf16(vv.w);
        }
        if (eq == 0) cnt[prow] = 0;   // reset by owning half-wave (in-order after reads)
    }

    // ---- single plain store (no atomics, every element covered exactly once) ----
    float* orow = out + ((size_t)(b * 1024 + t0 + prow)) * 128 + eq * 4;
    *reinterpret_cast<float4*>(orow) = (float4){oac[0], oac[1], oac[2], oac[3]};
}

extern "C" void kernel_launch(void* const* d_in, const int* in_sizes, int n_in,
                              void* d_out, int out_size, void* d_ws, size_t ws_size,
                              hipStream_t stream) {
    (void)in_sizes; (void)n_in; (void)ws_size; (void)out_size;
    const float* x   = (const float*)d_in[0];
    const int* mask  = (const int*)d_in[1];
    const float* wq  = (const float*)d_in[2];
    const float* wk  = (const float*)d_in[3];
    const float* wv  = (const float*)d_in[4];
    const float* wsl = (const float*)d_in[5];
    const float* bsl = (const float*)d_in[6];
    float* out = (float*)d_out;

    // ws layout: sel 8KB @0 | mp 1MB @8192 | xb 2MB | Wt 768KB | Q 16MB | K 16MB | V 16MB
    char* wsc = (char*)d_ws;
    float*    sel = (float*)wsc;
    u64*      mp  = (u64*)(wsc + 8192);
    ushort_t* xb  = (ushort_t*)(wsc + 8192 + 1048576);
    ushort_t* Wt  = (ushort_t*)(wsc + 8192 + 1048576 + 2097152);
    ushort_t* Qb  = (ushort_t*)(wsc + 8192 + 1048576 + 2097152 + 786432);
    ushort_t* Kb  = Qb + (size_t)8388608;
    ushort_t* Vb  = Kb + (size_t)8388608;

    prep_all<<<3120, 256, 0, stream>>>(x, xb, wq, wk, wv, Wt, mask, mp);
    sel_kernel<<<8, 1024, 0, stream>>>(x, wsl, bsl, sel);
    proj_gemm<<<dim3(128, 48), 256, 0, stream>>>(xb, Wt, Qb, Kb, Vb);
    attn_kernel<<<512, 512, 0, stream>>>(Qb, Kb, Vb, mp, sel, out);
}